// Round 7
// baseline (199.735 us; speedup 1.0000x reference)
//
#include <hip/hip_runtime.h>
#include <hip/hip_bf16.h>

typedef __bf16 bf16x8 __attribute__((ext_vector_type(8)));
typedef __bf16 bf16x4 __attribute__((ext_vector_type(4)));
typedef float floatx4 __attribute__((ext_vector_type(4)));
typedef float floatx16 __attribute__((ext_vector_type(16)));
using bf16 = __hip_bfloat16;

#define S_    2048
#define NHEAD 16
#define LOG2E 1.4426950408889634f

// Async global->LDS DMA, 16 B per lane (lane i -> lds + i*16).
__device__ __forceinline__ void load_lds16(const bf16* g, void* lds) {
  __builtin_amdgcn_global_load_lds((const __attribute__((address_space(1))) void*)g,
                                   (__attribute__((address_space(3))) void*)lds, 16, 0, 0);
}

// ---------------------------------------------------------------------------
// Fused prep: cast hidden fp32->bf16, transpose+cast weights, bias LUT.
// ---------------------------------------------------------------------------
__global__ void prep_kernel(const float* __restrict__ hidden,
                            const float* __restrict__ wq, const float* __restrict__ wk,
                            const float* __restrict__ wv, const float* __restrict__ wo,
                            const float* __restrict__ rel_bias,
                            bf16* __restrict__ hbf, bf16* __restrict__ wt_qkv,
                            bf16* __restrict__ wt_o, float* __restrict__ tab) {
  __shared__ bf16 tile[32][33];
  int bid = blockIdx.x;
  if (bid < 4096) {
    int i = (bid * 256 + threadIdx.x) * 4;
    float4 v = *(const float4*)(hidden + i);
    bf16 o[4] = {__float2bfloat16(v.x), __float2bfloat16(v.y),
                 __float2bfloat16(v.z), __float2bfloat16(v.w)};
    *(uint2*)(hbf + i) = *(const uint2*)o;
  } else if (bid < 8192) {
    int r = bid - 4096;
    int mat = r >> 10;
    int rem = r & 1023;
    int n0 = (rem & 31) * 32, k0 = (rem >> 5) * 32;
    int tx = threadIdx.x & 31, ty = threadIdx.x >> 5;   // 32 x 8
    const float* src = (mat == 0) ? wq : (mat == 1) ? wk : (mat == 2) ? wv : wo;
    bf16* dst = (mat == 3) ? wt_o : wt_qkv + mat * 1024 * 1024;
#pragma unroll
    for (int j = 0; j < 32; j += 8)
      tile[ty + j][tx] = __float2bfloat16(src[(k0 + ty + j) * 1024 + n0 + tx]);
    __syncthreads();
#pragma unroll
    for (int j = 0; j < 32; j += 8)
      dst[(n0 + ty + j) * 1024 + k0 + tx] = tile[tx][ty + j];
  } else {
    int idx = (bid - 8192) * 256 + threadIdx.x;  // 16*4096 = 65536
    int h = idx >> 12, j = idx & 4095;
    int delta = j - 2048;                        // k - q
    int rb = (delta > 0) ? 16 : 0;
    int rpa = delta < 0 ? -delta : delta;
    int bsmall;
    if (rpa < 8) {
      bsmall = rpa;
    } else {
      int lg = 25 - __clz(rpa * rpa);
      bsmall = 8 + lg;
      if (bsmall > 15) bsmall = 15;
    }
    tab[idx] = rel_bias[(rb + bsmall) * 16 + h] * LOG2E;
  }
}

// ---------------------------------------------------------------------------
// QKV GEMM, m97-style staging. Epilogue writes q head-major (qh[bh][s][64])
// and K/V in 32x32-MFMA fragment-major layouts:
//  kf(k,d): A-operand subtiles 32k x 16d (1KB): lane l=((d>>3)&1)*32+(k&31),
//           elem j=d&7 -> idx = (k>>5)*2048 + (d>>4)*512 + ((d>>3)&1)*256
//                              + (k&31)*8 + (d&7)
//  vf(k,d): B-operand subtiles 16k x 32d (1KB): lane l=((k>>3)&1)*32+(d&31),
//           elem j=k&7 -> idx = (k>>4)*1024 + (d>>5)*512 + ((k>>3)&1)*256
//                              + (d&31)*8 + (k&7)
// ---------------------------------------------------------------------------
__global__ __launch_bounds__(256) void gemm_qkv_kernel(const bf16* __restrict__ A,
                                                       const bf16* __restrict__ Bt,
                                                       bf16* __restrict__ qh,
                                                       bf16* __restrict__ kf,
                                                       bf16* __restrict__ vf) {
  const int K = 1024;
  __shared__ bf16 As[128 * 32];
  __shared__ bf16 Bs[128 * 32];
  int t = threadIdx.x;
  int m0 = blockIdx.y * 128, n0 = blockIdx.x * 128;
  int w = t >> 6, lane = t & 63, ln = lane & 15, quad = lane >> 4;
  int wr = w >> 1, wc = w & 1;
  floatx4 acc[4][4];
  floatx4 zero = {0.f, 0.f, 0.f, 0.f};
#pragma unroll
  for (int i = 0; i < 4; i++)
#pragma unroll
    for (int j = 0; j < 4; j++) acc[i][j] = zero;

  int r = t >> 2, c = (t & 3) * 8;
  const bf16* Ag = A + (long)(m0 + r) * K + c;
  const bf16* Bg = Bt + (long)(n0 + r) * K + c;
  char* ldsA0 = (char*)As + w * 1024;
  char* ldsA1 = ldsA0 + 4096;
  char* ldsB0 = (char*)Bs + w * 1024;
  char* ldsB1 = ldsB0 + 4096;

  for (int k0 = 0; k0 < K; k0 += 32) {
    load_lds16(Ag + k0, ldsA0);
    load_lds16(Ag + (long)64 * K + k0, ldsA1);
    load_lds16(Bg + k0, ldsB0);
    load_lds16(Bg + (long)64 * K + k0, ldsB1);
    __syncthreads();
    bf16x8 af[4], bfv[4];
#pragma unroll
    for (int i = 0; i < 4; i++)
      af[i] = *(const bf16x8*)&As[(wr * 64 + i * 16 + ln) * 32 + quad * 8];
#pragma unroll
    for (int j = 0; j < 4; j++)
      bfv[j] = *(const bf16x8*)&Bs[(wc * 64 + j * 16 + ln) * 32 + quad * 8];
#pragma unroll
    for (int i = 0; i < 4; i++)
#pragma unroll
      for (int j = 0; j < 4; j++)
        acc[i][j] = __builtin_amdgcn_mfma_f32_16x16x32_bf16(af[i], bfv[j], acc[i][j], 0, 0, 0);
    __syncthreads();
  }

  int nb = n0 + wc * 64;                        // 64-aligned column block
  int type = nb >> 10, h = (nb >> 6) & 15;
  int b = (m0 >> 11);                           // 128-tiles never straddle batch
  int sl0 = (m0 & 2047) + wr * 64;              // within-batch s base for this wave
  long bhbase = (long)((b * 16 + h)) * 131072;  // bh * 2048 * 64

  if (type == 0) {
#pragma unroll
    for (int i = 0; i < 4; i++)
#pragma unroll
      for (int j = 0; j < 4; j++) {
        int d = j * 16 + ln;
#pragma unroll
        for (int rr = 0; rr < 4; rr++) {
          int s = sl0 + i * 16 + quad * 4 + rr;
          qh[bhbase + (long)s * 64 + d] = __float2bfloat16(acc[i][j][rr]);
        }
      }
  } else if (type == 1) {
    // kf: k = sl0+i*16+quad*4+rr, d = j*16+ln
#pragma unroll
    for (int i = 0; i < 4; i++)
#pragma unroll
      for (int j = 0; j < 4; j++) {
        long base = bhbase + sl0 * 64 + (i >> 1) * 2048 + j * 512 + (ln >> 3) * 256 +
                    (i & 1) * 128 + quad * 32 + (ln & 7);
#pragma unroll
        for (int rr = 0; rr < 4; rr++)
          kf[base + rr * 8] = __float2bfloat16(acc[i][j][rr]);
      }
  } else {
    // vf: k = sl0+i*16+quad*4+rr, d = j*16+ln  (rr contiguous -> 8B store)
#pragma unroll
    for (int i = 0; i < 4; i++)
#pragma unroll
      for (int j = 0; j < 4; j++) {
        long off = sl0 * 64 + i * 1024 + (j >> 1) * 512 + (quad >> 1) * 256 +
                   ((j & 1) * 16 + ln) * 8 + (quad & 1) * 4;
        bf16x4 pk = {(__bf16)acc[i][j][0], (__bf16)acc[i][j][1],
                     (__bf16)acc[i][j][2], (__bf16)acc[i][j][3]};
        *(bf16x4*)(vf + bhbase + off) = pk;
      }
  }
}

// ---------------------------------------------------------------------------
// Flash attention v7 = r6 structure (52.4us, 88 VGPR, no spill) + k-split x2
// for TLP: waves 0/1 do k[0,1024), waves 2/3 do k[1024,2048) for the same
// 64 q rows; exp-softmax (no running max) => partials merge ADDITIVELY via a
// 16.9KB LDS buffer + single end barrier. Grid 1024 = 4 blocks/CU = 4
// waves/SIMD (was 2). KEEP __launch_bounds__(256,2): r5 proved min-waves=4
// caps unified VGPR at 128 and spills the hot loop (805MB scratch traffic).
// ---------------------------------------------------------------------------
#define LOADKV(Kr, Vr, kk)                                        \
  {                                                               \
    const bf16* kp = kfb + (kk) * 64 + loff;                      \
    const bf16* vp = vfb + (kk) * 64 + loff;                      \
    Kr[0] = *(const bf16x8*)(kp);                                 \
    Kr[1] = *(const bf16x8*)(kp + 512);                           \
    Kr[2] = *(const bf16x8*)(kp + 1024);                          \
    Kr[3] = *(const bf16x8*)(kp + 1536);                          \
    Vr[0] = *(const bf16x8*)(vp);                                 \
    Vr[1] = *(const bf16x8*)(vp + 512);                           \
    Vr[2] = *(const bf16x8*)(vp + 1024);                          \
    Vr[3] = *(const bf16x8*)(vp + 1536);                          \
  }

#define COMPUTE(Kr, Vr, kk)                                                       \
  {                                                                               \
    floatx16 st = zf;                                                             \
    __builtin_amdgcn_s_setprio(1);                                                \
    st = __builtin_amdgcn_mfma_f32_32x32x16_bf16(Kr[0], Qf[0], st, 0, 0, 0);      \
    st = __builtin_amdgcn_mfma_f32_32x32x16_bf16(Kr[1], Qf[1], st, 0, 0, 0);      \
    st = __builtin_amdgcn_mfma_f32_32x32x16_bf16(Kr[2], Qf[2], st, 0, 0, 0);      \
    st = __builtin_amdgcn_mfma_f32_32x32x16_bf16(Kr[3], Qf[3], st, 0, 0, 0);      \
    __builtin_amdgcn_s_setprio(0);                                                \
    float p[16];                                                                  \
    bool near = ((kk) > qw - 160) && ((kk) < qw + 160);                           \
    if (near) {                                                                   \
      int kb = (kk) + 4 * h5 - (qw + l31) + 2048;                                 \
      _Pragma("unroll")                                                           \
      for (int r = 0; r < 16; r++)                                                \
        p[r] = __builtin_amdgcn_exp2f(                                            \
            fmaf(st[r], LOG2E, bt[kb + (r & 3) + 8 * (r >> 2)]));                 \
    } else {                                                                      \
      float cb = ((kk) > qw) ? cpos : cneg;                                       \
      _Pragma("unroll")                                                           \
      for (int r = 0; r < 16; r++)                                                \
        p[r] = __builtin_amdgcn_exp2f(fmaf(st[r], LOG2E, cb));                    \
    }                                                                             \
    float a0 = (p[0] + p[1]) + (p[2] + p[3]);                                     \
    float a1 = (p[4] + p[5]) + (p[6] + p[7]);                                     \
    float a2 = (p[8] + p[9]) + (p[10] + p[11]);                                   \
    float a3 = (p[12] + p[13]) + (p[14] + p[15]);                                 \
    l_acc += (a0 + a1) + (a2 + a3);                                               \
    unsigned d[8];                                                                \
    _Pragma("unroll")                                                             \
    for (int i = 0; i < 8; i++)                                                   \
      asm("v_cvt_pk_bf16_f32 %0, %1, %2" : "=v"(d[i]) : "v"(p[2*i]), "v"(p[2*i+1])); \
    unsigned w0 = d[0], w2 = d[2];                                                \
    asm("v_permlane32_swap_b32 %0, %1" : "+v"(w0), "+v"(w2));                     \
    unsigned w1 = d[1], w3 = d[3];                                                \
    asm("v_permlane32_swap_b32 %0, %1" : "+v"(w1), "+v"(w3));                     \
    unsigned w4 = d[4], w6 = d[6];                                                \
    asm("v_permlane32_swap_b32 %0, %1" : "+v"(w4), "+v"(w6));                     \
    unsigned w5 = d[5], w7 = d[7];                                                \
    asm("v_permlane32_swap_b32 %0, %1" : "+v"(w5), "+v"(w7));                     \
    union { unsigned u[4]; bf16x8 v; } a0u, a1u;                                  \
    a0u.u[0] = w0; a0u.u[1] = w1; a0u.u[2] = w2; a0u.u[3] = w3;                   \
    a1u.u[0] = w4; a1u.u[1] = w5; a1u.u[2] = w6; a1u.u[3] = w7;                   \
    __builtin_amdgcn_s_setprio(1);                                                \
    o0 = __builtin_amdgcn_mfma_f32_32x32x16_bf16(a0u.v, Vr[0], o0, 0, 0, 0);      \
    o1 = __builtin_amdgcn_mfma_f32_32x32x16_bf16(a0u.v, Vr[1], o1, 0, 0, 0);      \
    o0 = __builtin_amdgcn_mfma_f32_32x32x16_bf16(a1u.v, Vr[2], o0, 0, 0, 0);      \
    o1 = __builtin_amdgcn_mfma_f32_32x32x16_bf16(a1u.v, Vr[3], o1, 0, 0, 0);      \
    __builtin_amdgcn_s_setprio(0);                                                \
  }

__global__ __launch_bounds__(256, 2) void attn_kernel(const bf16* __restrict__ qh,
                                                      const bf16* __restrict__ kf,
                                                      const bf16* __restrict__ vf,
                                                      const float* __restrict__ btab,
                                                      bf16* __restrict__ ctx) {
  __shared__ float mbuf[2][64][33];            // k-split merge buffer (16.9 KB)
  int t = threadIdx.x, w = t >> 6, lane = t & 63;
  int l31 = lane & 31, h5 = lane >> 5;

  // XCD-ownership swizzle: 1024 blocks; xcd = lin&7 owns 4 consecutive bh
  // (all 32 qblk of them) -> per-XCD L2 set = 4 x (0.5 MB KV + 0.25 MB Q).
  int lin = blockIdx.x;
  int xcd = lin & 7, j = lin >> 3;             // j in [0,128)
  int bh = xcd * 4 + (j >> 5);
  int qblk = j & 31;
  int b = bh >> 4, h = bh & 15;
  int qw = qblk * 64 + (w & 1) * 32;           // this wave's first q row
  int kbeg = (w >> 1) * 1024;                  // k-split: half range per wave pair

  const bf16* qbase = qh + (long)bh * S_ * 64;
  const bf16* kfb = kf + (long)bh * S_ * 64;
  const bf16* vfb = vf + (long)bh * S_ * 64;
  const float* bt = btab + h * 4096;
  int loff = h5 * 256 + l31 * 8;               // lane offset inside 1KB frag (elems)

  // Q as B-operand: col = q = l31, k-of-slice = h5*8 + j (d-slice ds of 16)
  bf16x8 Qf[4];
#pragma unroll
  for (int ds = 0; ds < 4; ds++)
    Qf[ds] = *(const bf16x8*)(qbase + (long)(qw + l31) * 64 + ds * 16 + h5 * 8);

  float cneg = bt[0], cpos = bt[4095];
  float l_acc = 0.f;
  floatx16 zf = {0.f, 0.f, 0.f, 0.f, 0.f, 0.f, 0.f, 0.f,
                 0.f, 0.f, 0.f, 0.f, 0.f, 0.f, 0.f, 0.f};
  floatx16 o0 = zf, o1 = zf;

  bf16x8 Ka[4], Va[4], Kb[4], Vb[4];
  LOADKV(Ka, Va, kbeg);
  LOADKV(Kb, Vb, kbeg + 32);

  int kend = kbeg + 1024;
  for (int k0 = kbeg; k0 < kend; k0 += 64) {
    COMPUTE(Ka, Va, k0);
    if (k0 + 64 < kend) LOADKV(Ka, Va, k0 + 64);
    COMPUTE(Kb, Vb, k0 + 32);
    if (k0 + 96 < kend) LOADKV(Kb, Vb, k0 + 96);
  }

  // combine the two k-16-halves within the wave
  l_acc += __shfl_xor(l_acc, 32);

  // k-split merge: waves 2/3 publish partial {o,l}; waves 0/1 add + store.
  if (w >= 2) {
    float* dst = &mbuf[w & 1][lane][0];
#pragma unroll
    for (int r = 0; r < 16; r++) { dst[r] = o0[r]; dst[16 + r] = o1[r]; }
    dst[32] = l_acc;
  }
  __syncthreads();
  if (w < 2) {
    const float* src = &mbuf[w][lane][0];
#pragma unroll
    for (int r = 0; r < 16; r++) { o0[r] += src[r]; o1[r] += src[16 + r]; }
    l_acc += src[32];
    float linv = 1.0f / l_acc;                 // for q = qw + l31
#pragma unroll
    for (int r = 0; r < 16; r++) {
      int qrow = (r & 3) + 8 * (r >> 2) + 4 * h5;
      float lv = __shfl(linv, qrow);
      int q = qw + qrow;
      long base = (long)(b * S_ + q) * 1024 + h * 64 + l31;
      ctx[base] = __float2bfloat16(o0[r] * lv);
      ctx[base + 32] = __float2bfloat16(o1[r] * lv);
    }
  }
}

// ---------------------------------------------------------------------------
// Out-proj GEMM: C[M][N] = A[M][K] * Bt[N][K]^T (fp32 out), m97-style staging.
// ---------------------------------------------------------------------------
__global__ __launch_bounds__(256) void gemm_bt_kernel(const bf16* __restrict__ A,
                                                      const bf16* __restrict__ Bt,
                                                      float* __restrict__ C,
                                                      int M, int N, int K) {
  __shared__ bf16 As[128 * 32];
  __shared__ bf16 Bs[128 * 32];
  int t = threadIdx.x;
  int m0 = blockIdx.y * 128, n0 = blockIdx.x * 128;
  int w = t >> 6, lane = t & 63, ln = lane & 15, quad = lane >> 4;
  int wr = w >> 1, wc = w & 1;
  floatx4 acc[4][4];
  floatx4 zero = {0.f, 0.f, 0.f, 0.f};
#pragma unroll
  for (int i = 0; i < 4; i++)
#pragma unroll
    for (int j = 0; j < 4; j++) acc[i][j] = zero;

  int r = t >> 2, c = (t & 3) * 8;
  const bf16* Ag = A + (long)(m0 + r) * K + c;
  const bf16* Bg = Bt + (long)(n0 + r) * K + c;
  char* ldsA0 = (char*)As + w * 1024;
  char* ldsA1 = ldsA0 + 4096;
  char* ldsB0 = (char*)Bs + w * 1024;
  char* ldsB1 = ldsB0 + 4096;

  for (int k0 = 0; k0 < K; k0 += 32) {
    load_lds16(Ag + k0, ldsA0);
    load_lds16(Ag + (long)64 * K + k0, ldsA1);
    load_lds16(Bg + k0, ldsB0);
    load_lds16(Bg + (long)64 * K + k0, ldsB1);
    __syncthreads();
    bf16x8 af[4], bfv[4];
#pragma unroll
    for (int i = 0; i < 4; i++)
      af[i] = *(const bf16x8*)&As[(wr * 64 + i * 16 + ln) * 32 + quad * 8];
#pragma unroll
    for (int j = 0; j < 4; j++)
      bfv[j] = *(const bf16x8*)&Bs[(wc * 64 + j * 16 + ln) * 32 + quad * 8];
#pragma unroll
    for (int i = 0; i < 4; i++)
#pragma unroll
      for (int j = 0; j < 4; j++)
        acc[i][j] = __builtin_amdgcn_mfma_f32_16x16x32_bf16(af[i], bfv[j], acc[i][j], 0, 0, 0);
    __syncthreads();
  }

#pragma unroll
  for (int i = 0; i < 4; i++)
#pragma unroll
    for (int j = 0; j < 4; j++)
#pragma unroll
      for (int rr = 0; rr < 4; rr++)
        C[(long)(m0 + wr * 64 + i * 16 + quad * 4 + rr) * N + n0 + wc * 64 + j * 16 + ln] =
            acc[i][j][rr];
}

// ---------------------------------------------------------------------------
extern "C" void kernel_launch(void* const* d_in, const int* in_sizes, int n_in,
                              void* d_out, int out_size, void* d_ws, size_t ws_size,
                              hipStream_t stream) {
  (void)in_sizes; (void)n_in; (void)out_size; (void)ws_size;
  const float* hidden   = (const float*)d_in[0];
  const float* Wq       = (const float*)d_in[1];
  const float* Wk       = (const float*)d_in[2];
  const float* Wv       = (const float*)d_in[3];
  const float* Wo       = (const float*)d_in[4];
  const float* rel_bias = (const float*)d_in[5];

  char* ws = (char*)d_ws;
  bf16*  hbf    = (bf16*)(ws + 0);                 //  8 MB [4096][1024]
  bf16*  wt_qkv = (bf16*)(ws + 8388608);           //  6 MB
  bf16*  wt_o   = (bf16*)(ws + 14680064);          //  2 MB
  float* btab   = (float*)(ws + 16777216);         // 256 KB
  bf16*  qh     = (bf16*)(ws + 17039360);          //  8 MB head-major Q
  bf16*  kf     = (bf16*)(ws + 25427968);          //  8 MB frag-major K
  bf16*  vf     = (bf16*)(ws + 33816576);          //  8 MB frag-major V
  bf16*  ctx    = (bf16*)(ws + 42205184);          //  8 MB

  prep_kernel<<<dim3(8448), dim3(256), 0, stream>>>(hidden, Wq, Wk, Wv, Wo, rel_bias,
                                                    hbf, wt_qkv, wt_o, btab);
  gemm_qkv_kernel<<<dim3(24, 32), dim3(256), 0, stream>>>(hbf, wt_qkv, qh, kf, vf);
  attn_kernel<<<dim3(1024), dim3(256), 0, stream>>>(qh, kf, vf, btab, ctx);
  gemm_bt_kernel<<<dim3(8, 32), dim3(256), 0, stream>>>(ctx, wt_o, (float*)d_out, 4096, 1024, 1024);
}

// Round 8
// 198.659 us; speedup vs baseline: 1.0054x; 1.0054x over previous
//
#include <hip/hip_runtime.h>
#include <hip/hip_bf16.h>

typedef __bf16 bf16x8 __attribute__((ext_vector_type(8)));
typedef __bf16 bf16x4 __attribute__((ext_vector_type(4)));
typedef float floatx4 __attribute__((ext_vector_type(4)));
typedef float floatx16 __attribute__((ext_vector_type(16)));
using bf16 = __hip_bfloat16;

#define S_    2048
#define NHEAD 16
#define LOG2E 1.4426950408889634f

// Async global->LDS DMA, 16 B per lane (lane i -> lds + i*16).
__device__ __forceinline__ void load_lds16(const bf16* g, void* lds) {
  __builtin_amdgcn_global_load_lds((const __attribute__((address_space(1))) void*)g,
                                   (__attribute__((address_space(3))) void*)lds, 16, 0, 0);
}

// ---------------------------------------------------------------------------
// Fused prep: cast hidden fp32->bf16, transpose+cast weights, bias LUT.
// ---------------------------------------------------------------------------
__global__ void prep_kernel(const float* __restrict__ hidden,
                            const float* __restrict__ wq, const float* __restrict__ wk,
                            const float* __restrict__ wv, const float* __restrict__ wo,
                            const float* __restrict__ rel_bias,
                            bf16* __restrict__ hbf, bf16* __restrict__ wt_qkv,
                            bf16* __restrict__ wt_o, float* __restrict__ tab) {
  __shared__ bf16 tile[32][33];
  int bid = blockIdx.x;
  if (bid < 4096) {
    int i = (bid * 256 + threadIdx.x) * 4;
    float4 v = *(const float4*)(hidden + i);
    bf16 o[4] = {__float2bfloat16(v.x), __float2bfloat16(v.y),
                 __float2bfloat16(v.z), __float2bfloat16(v.w)};
    *(uint2*)(hbf + i) = *(const uint2*)o;
  } else if (bid < 8192) {
    int r = bid - 4096;
    int mat = r >> 10;
    int rem = r & 1023;
    int n0 = (rem & 31) * 32, k0 = (rem >> 5) * 32;
    int tx = threadIdx.x & 31, ty = threadIdx.x >> 5;   // 32 x 8
    const float* src = (mat == 0) ? wq : (mat == 1) ? wk : (mat == 2) ? wv : wo;
    bf16* dst = (mat == 3) ? wt_o : wt_qkv + mat * 1024 * 1024;
#pragma unroll
    for (int j = 0; j < 32; j += 8)
      tile[ty + j][tx] = __float2bfloat16(src[(k0 + ty + j) * 1024 + n0 + tx]);
    __syncthreads();
#pragma unroll
    for (int j = 0; j < 32; j += 8)
      dst[(n0 + ty + j) * 1024 + k0 + tx] = tile[tx][ty + j];
  } else {
    int idx = (bid - 8192) * 256 + threadIdx.x;  // 16*4096 = 65536
    int h = idx >> 12, j = idx & 4095;
    int delta = j - 2048;                        // k - q
    int rb = (delta > 0) ? 16 : 0;
    int rpa = delta < 0 ? -delta : delta;
    int bsmall;
    if (rpa < 8) {
      bsmall = rpa;
    } else {
      int lg = 25 - __clz(rpa * rpa);
      bsmall = 8 + lg;
      if (bsmall > 15) bsmall = 15;
    }
    tab[idx] = rel_bias[(rb + bsmall) * 16 + h] * LOG2E;
  }
}

// ---------------------------------------------------------------------------
// QKV GEMM, m97-style staging. Epilogue writes q head-major (qh[bh][s][64])
// and K/V in 32x32-MFMA fragment-major layouts:
//  kf(k,d): A-operand subtiles 32k x 16d (1KB): lane l=((d>>3)&1)*32+(k&31),
//           elem j=d&7 -> idx = (k>>5)*2048 + (d>>4)*512 + ((d>>3)&1)*256
//                              + (k&31)*8 + (d&7)
//  vf(k,d): B-operand subtiles 16k x 32d (1KB): lane l=((k>>3)&1)*32+(d&31),
//           elem j=k&7 -> idx = (k>>4)*1024 + (d>>5)*512 + ((k>>3)&1)*256
//                              + (d&31)*8 + (k&7)
// ---------------------------------------------------------------------------
__global__ __launch_bounds__(256) void gemm_qkv_kernel(const bf16* __restrict__ A,
                                                       const bf16* __restrict__ Bt,
                                                       bf16* __restrict__ qh,
                                                       bf16* __restrict__ kf,
                                                       bf16* __restrict__ vf) {
  const int K = 1024;
  __shared__ bf16 As[128 * 32];
  __shared__ bf16 Bs[128 * 32];
  int t = threadIdx.x;
  int m0 = blockIdx.y * 128, n0 = blockIdx.x * 128;
  int w = t >> 6, lane = t & 63, ln = lane & 15, quad = lane >> 4;
  int wr = w >> 1, wc = w & 1;
  floatx4 acc[4][4];
  floatx4 zero = {0.f, 0.f, 0.f, 0.f};
#pragma unroll
  for (int i = 0; i < 4; i++)
#pragma unroll
    for (int j = 0; j < 4; j++) acc[i][j] = zero;

  int r = t >> 2, c = (t & 3) * 8;
  const bf16* Ag = A + (long)(m0 + r) * K + c;
  const bf16* Bg = Bt + (long)(n0 + r) * K + c;
  char* ldsA0 = (char*)As + w * 1024;
  char* ldsA1 = ldsA0 + 4096;
  char* ldsB0 = (char*)Bs + w * 1024;
  char* ldsB1 = ldsB0 + 4096;

  for (int k0 = 0; k0 < K; k0 += 32) {
    load_lds16(Ag + k0, ldsA0);
    load_lds16(Ag + (long)64 * K + k0, ldsA1);
    load_lds16(Bg + k0, ldsB0);
    load_lds16(Bg + (long)64 * K + k0, ldsB1);
    __syncthreads();
    bf16x8 af[4], bfv[4];
#pragma unroll
    for (int i = 0; i < 4; i++)
      af[i] = *(const bf16x8*)&As[(wr * 64 + i * 16 + ln) * 32 + quad * 8];
#pragma unroll
    for (int j = 0; j < 4; j++)
      bfv[j] = *(const bf16x8*)&Bs[(wc * 64 + j * 16 + ln) * 32 + quad * 8];
#pragma unroll
    for (int i = 0; i < 4; i++)
#pragma unroll
      for (int j = 0; j < 4; j++)
        acc[i][j] = __builtin_amdgcn_mfma_f32_16x16x32_bf16(af[i], bfv[j], acc[i][j], 0, 0, 0);
    __syncthreads();
  }

  int nb = n0 + wc * 64;                        // 64-aligned column block
  int type = nb >> 10, h = (nb >> 6) & 15;
  int b = (m0 >> 11);                           // 128-tiles never straddle batch
  int sl0 = (m0 & 2047) + wr * 64;              // within-batch s base for this wave
  long bhbase = (long)((b * 16 + h)) * 131072;  // bh * 2048 * 64

  if (type == 0) {
#pragma unroll
    for (int i = 0; i < 4; i++)
#pragma unroll
      for (int j = 0; j < 4; j++) {
        int d = j * 16 + ln;
#pragma unroll
        for (int rr = 0; rr < 4; rr++) {
          int s = sl0 + i * 16 + quad * 4 + rr;
          qh[bhbase + (long)s * 64 + d] = __float2bfloat16(acc[i][j][rr]);
        }
      }
  } else if (type == 1) {
    // kf: k = sl0+i*16+quad*4+rr, d = j*16+ln
#pragma unroll
    for (int i = 0; i < 4; i++)
#pragma unroll
      for (int j = 0; j < 4; j++) {
        long base = bhbase + sl0 * 64 + (i >> 1) * 2048 + j * 512 + (ln >> 3) * 256 +
                    (i & 1) * 128 + quad * 32 + (ln & 7);
#pragma unroll
        for (int rr = 0; rr < 4; rr++)
          kf[base + rr * 8] = __float2bfloat16(acc[i][j][rr]);
      }
  } else {
    // vf: k = sl0+i*16+quad*4+rr, d = j*16+ln  (rr contiguous -> 8B store)
#pragma unroll
    for (int i = 0; i < 4; i++)
#pragma unroll
      for (int j = 0; j < 4; j++) {
        long off = sl0 * 64 + i * 1024 + (j >> 1) * 512 + (quad >> 1) * 256 +
                   ((j & 1) * 16 + ln) * 8 + (quad & 1) * 4;
        bf16x4 pk = {(__bf16)acc[i][j][0], (__bf16)acc[i][j][1],
                     (__bf16)acc[i][j][2], (__bf16)acc[i][j][3]};
        *(bf16x4*)(vf + bhbase + off) = pk;
      }
  }
}

// ---------------------------------------------------------------------------
// Flash attention v8: k-split x2 (r7) + SINGLE-buffer K/V registers.
// r7 evidence: OccupancyPercent stayed 17% because VGPR(96) + AGPR(~64) ~ 160
// total regs -> 8 waves/CU hardware cap; k-split gave no TLP. This version
// drops the K/V double-buffer (-32 regs): K(t+1) is loaded right after QK(t)
// consumes Kr (lands during softmax+PV), V(t+1) right after PV(t) consumes Vr
// (lands during next QK+softmax) -- same latency cover, half the registers.
// Target total <= 128 regs -> 16 waves/CU -> k-split TLP becomes real.
// KEEP __launch_bounds__(256,2) (r5: forcing 4 spills the loop).
// ---------------------------------------------------------------------------
__global__ __launch_bounds__(256, 2) void attn_kernel(const bf16* __restrict__ qh,
                                                      const bf16* __restrict__ kf,
                                                      const bf16* __restrict__ vf,
                                                      const float* __restrict__ btab,
                                                      bf16* __restrict__ ctx) {
  __shared__ float mbuf[2][64][33];            // k-split merge buffer (16.9 KB)
  int t = threadIdx.x, w = t >> 6, lane = t & 63;
  int l31 = lane & 31, h5 = lane >> 5;

  // XCD-ownership swizzle: 1024 blocks; xcd = lin&7 owns 4 consecutive bh.
  int lin = blockIdx.x;
  int xcd = lin & 7, j = lin >> 3;             // j in [0,128)
  int bh = xcd * 4 + (j >> 5);
  int qblk = j & 31;
  int b = bh >> 4, h = bh & 15;
  int qw = qblk * 64 + (w & 1) * 32;           // this wave's first q row
  int kbeg = (w >> 1) * 1024;                  // k-split: half range per wave pair

  const bf16* qbase = qh + (long)bh * S_ * 64;
  const bf16* kfb = kf + (long)bh * S_ * 64;
  const bf16* vfb = vf + (long)bh * S_ * 64;
  const float* bt = btab + h * 4096;
  int loff = h5 * 256 + l31 * 8;               // lane offset inside 1KB frag (elems)

  // Q as B-operand: col = q = l31, k-of-slice = h5*8 + j (d-slice ds of 16)
  bf16x8 Qf[4];
#pragma unroll
  for (int ds = 0; ds < 4; ds++)
    Qf[ds] = *(const bf16x8*)(qbase + (long)(qw + l31) * 64 + ds * 16 + h5 * 8);

  float cneg = bt[0], cpos = bt[4095];
  float l_acc = 0.f;
  floatx16 zf = {0.f, 0.f, 0.f, 0.f, 0.f, 0.f, 0.f, 0.f,
                 0.f, 0.f, 0.f, 0.f, 0.f, 0.f, 0.f, 0.f};
  floatx16 o0 = zf, o1 = zf;

  bf16x8 Kr[4], Vr[4];
  {
    const bf16* kp = kfb + kbeg * 64 + loff;
    Kr[0] = *(const bf16x8*)(kp);
    Kr[1] = *(const bf16x8*)(kp + 512);
    Kr[2] = *(const bf16x8*)(kp + 1024);
    Kr[3] = *(const bf16x8*)(kp + 1536);
    const bf16* vp = vfb + kbeg * 64 + loff;
    Vr[0] = *(const bf16x8*)(vp);
    Vr[1] = *(const bf16x8*)(vp + 512);
    Vr[2] = *(const bf16x8*)(vp + 1024);
    Vr[3] = *(const bf16x8*)(vp + 1536);
  }

  int kend = kbeg + 1024;
  for (int k0 = kbeg; k0 < kend; k0 += 32) {
    int kn = k0 + 32;
    // QK^T swapped: A=K rows=k, B=Q cols=q -> S^T[k][q]
    floatx16 st = zf;
    __builtin_amdgcn_s_setprio(1);
    st = __builtin_amdgcn_mfma_f32_32x32x16_bf16(Kr[0], Qf[0], st, 0, 0, 0);
    st = __builtin_amdgcn_mfma_f32_32x32x16_bf16(Kr[1], Qf[1], st, 0, 0, 0);
    st = __builtin_amdgcn_mfma_f32_32x32x16_bf16(Kr[2], Qf[2], st, 0, 0, 0);
    st = __builtin_amdgcn_mfma_f32_32x32x16_bf16(Kr[3], Qf[3], st, 0, 0, 0);
    __builtin_amdgcn_s_setprio(0);
    // prefetch next K into the SAME regs (WAR-safe: QK above consumed them;
    // lands during softmax+PV, waited by next iteration's first MFMA)
    if (kn < kend) {
      const bf16* kp = kfb + kn * 64 + loff;
      Kr[0] = *(const bf16x8*)(kp);
      Kr[1] = *(const bf16x8*)(kp + 512);
      Kr[2] = *(const bf16x8*)(kp + 1024);
      Kr[3] = *(const bf16x8*)(kp + 1536);
    }

    // softmax in-register: p = exp2(st*LOG2E + bias); lane q = qw+l31,
    // k = k0 + (r&3) + 8*(r>>2) + 4*h5.
    float p[16];
    bool near = (k0 > qw - 160) && (k0 < qw + 160);
    if (near) {
      int kb = k0 + 4 * h5 - (qw + l31) + 2048;
#pragma unroll
      for (int r = 0; r < 16; r++)
        p[r] = __builtin_amdgcn_exp2f(
            fmaf(st[r], LOG2E, bt[kb + (r & 3) + 8 * (r >> 2)]));
    } else {
      float cb = (k0 > qw) ? cpos : cneg;
#pragma unroll
      for (int r = 0; r < 16; r++)
        p[r] = __builtin_amdgcn_exp2f(fmaf(st[r], LOG2E, cb));
    }
    float a0 = (p[0] + p[1]) + (p[2] + p[3]);
    float a1 = (p[4] + p[5]) + (p[6] + p[7]);
    float a2 = (p[8] + p[9]) + (p[10] + p[11]);
    float a3 = (p[12] + p[13]) + (p[14] + p[15]);
    l_acc += (a0 + a1) + (a2 + a3);

    unsigned d[8];
#pragma unroll
    for (int i = 0; i < 8; i++)
      asm("v_cvt_pk_bf16_f32 %0, %1, %2" : "=v"(d[i]) : "v"(p[2 * i]), "v"(p[2 * i + 1]));
    unsigned w0 = d[0], w2 = d[2];
    asm("v_permlane32_swap_b32 %0, %1" : "+v"(w0), "+v"(w2));
    unsigned w1 = d[1], w3 = d[3];
    asm("v_permlane32_swap_b32 %0, %1" : "+v"(w1), "+v"(w3));
    unsigned w4 = d[4], w6 = d[6];
    asm("v_permlane32_swap_b32 %0, %1" : "+v"(w4), "+v"(w6));
    unsigned w5 = d[5], w7 = d[7];
    asm("v_permlane32_swap_b32 %0, %1" : "+v"(w5), "+v"(w7));
    union { unsigned u[4]; bf16x8 v; } a0u, a1u;
    a0u.u[0] = w0; a0u.u[1] = w1; a0u.u[2] = w2; a0u.u[3] = w3;
    a1u.u[0] = w4; a1u.u[1] = w5; a1u.u[2] = w6; a1u.u[3] = w7;

    // PV: A = P (rows=q), B = V (cols=dv)
    __builtin_amdgcn_s_setprio(1);
    o0 = __builtin_amdgcn_mfma_f32_32x32x16_bf16(a0u.v, Vr[0], o0, 0, 0, 0);
    o1 = __builtin_amdgcn_mfma_f32_32x32x16_bf16(a0u.v, Vr[1], o1, 0, 0, 0);
    o0 = __builtin_amdgcn_mfma_f32_32x32x16_bf16(a1u.v, Vr[2], o0, 0, 0, 0);
    o1 = __builtin_amdgcn_mfma_f32_32x32x16_bf16(a1u.v, Vr[3], o1, 0, 0, 0);
    __builtin_amdgcn_s_setprio(0);
    // prefetch next V into the SAME regs (WAR-safe: PV above consumed them;
    // lands during next iteration's QK+softmax)
    if (kn < kend) {
      const bf16* vp = vfb + kn * 64 + loff;
      Vr[0] = *(const bf16x8*)(vp);
      Vr[1] = *(const bf16x8*)(vp + 512);
      Vr[2] = *(const bf16x8*)(vp + 1024);
      Vr[3] = *(const bf16x8*)(vp + 1536);
    }
  }

  // combine the two k-16-halves within the wave
  l_acc += __shfl_xor(l_acc, 32);

  // k-split merge: waves 2/3 publish partial {o,l}; waves 0/1 add + store.
  if (w >= 2) {
    float* dst = &mbuf[w & 1][lane][0];
#pragma unroll
    for (int r = 0; r < 16; r++) { dst[r] = o0[r]; dst[16 + r] = o1[r]; }
    dst[32] = l_acc;
  }
  __syncthreads();
  if (w < 2) {
    const float* src = &mbuf[w][lane][0];
#pragma unroll
    for (int r = 0; r < 16; r++) { o0[r] += src[r]; o1[r] += src[16 + r]; }
    l_acc += src[32];
    float linv = 1.0f / l_acc;                 // for q = qw + l31
#pragma unroll
    for (int r = 0; r < 16; r++) {
      int qrow = (r & 3) + 8 * (r >> 2) + 4 * h5;
      float lv = __shfl(linv, qrow);
      int q = qw + qrow;
      long base = (long)(b * S_ + q) * 1024 + h * 64 + l31;
      ctx[base] = __float2bfloat16(o0[r] * lv);
      ctx[base + 32] = __float2bfloat16(o1[r] * lv);
    }
  }
}

// ---------------------------------------------------------------------------
// Out-proj GEMM: C[M][N] = A[M][K] * Bt[N][K]^T (fp32 out), m97-style staging.
// ---------------------------------------------------------------------------
__global__ __launch_bounds__(256) void gemm_bt_kernel(const bf16* __restrict__ A,
                                                      const bf16* __restrict__ Bt,
                                                      float* __restrict__ C,
                                                      int M, int N, int K) {
  __shared__ bf16 As[128 * 32];
  __shared__ bf16 Bs[128 * 32];
  int t = threadIdx.x;
  int m0 = blockIdx.y * 128, n0 = blockIdx.x * 128;
  int w = t >> 6, lane = t & 63, ln = lane & 15, quad = lane >> 4;
  int wr = w >> 1, wc = w & 1;
  floatx4 acc[4][4];
  floatx4 zero = {0.f, 0.f, 0.f, 0.f};
#pragma unroll
  for (int i = 0; i < 4; i++)
#pragma unroll
    for (int j = 0; j < 4; j++) acc[i][j] = zero;

  int r = t >> 2, c = (t & 3) * 8;
  const bf16* Ag = A + (long)(m0 + r) * K + c;
  const bf16* Bg = Bt + (long)(n0 + r) * K + c;
  char* ldsA0 = (char*)As + w * 1024;
  char* ldsA1 = ldsA0 + 4096;
  char* ldsB0 = (char*)Bs + w * 1024;
  char* ldsB1 = ldsB0 + 4096;

  for (int k0 = 0; k0 < K; k0 += 32) {
    load_lds16(Ag + k0, ldsA0);
    load_lds16(Ag + (long)64 * K + k0, ldsA1);
    load_lds16(Bg + k0, ldsB0);
    load_lds16(Bg + (long)64 * K + k0, ldsB1);
    __syncthreads();
    bf16x8 af[4], bfv[4];
#pragma unroll
    for (int i = 0; i < 4; i++)
      af[i] = *(const bf16x8*)&As[(wr * 64 + i * 16 + ln) * 32 + quad * 8];
#pragma unroll
    for (int j = 0; j < 4; j++)
      bfv[j] = *(const bf16x8*)&Bs[(wc * 64 + j * 16 + ln) * 32 + quad * 8];
#pragma unroll
    for (int i = 0; i < 4; i++)
#pragma unroll
      for (int j = 0; j < 4; j++)
        acc[i][j] = __builtin_amdgcn_mfma_f32_16x16x32_bf16(af[i], bfv[j], acc[i][j], 0, 0, 0);
    __syncthreads();
  }

#pragma unroll
  for (int i = 0; i < 4; i++)
#pragma unroll
    for (int j = 0; j < 4; j++)
#pragma unroll
      for (int rr = 0; rr < 4; rr++)
        C[(long)(m0 + wr * 64 + i * 16 + quad * 4 + rr) * N + n0 + wc * 64 + j * 16 + ln] =
            acc[i][j][rr];
}

// ---------------------------------------------------------------------------
extern "C" void kernel_launch(void* const* d_in, const int* in_sizes, int n_in,
                              void* d_out, int out_size, void* d_ws, size_t ws_size,
                              hipStream_t stream) {
  (void)in_sizes; (void)n_in; (void)out_size; (void)ws_size;
  const float* hidden   = (const float*)d_in[0];
  const float* Wq       = (const float*)d_in[1];
  const float* Wk       = (const float*)d_in[2];
  const float* Wv       = (const float*)d_in[3];
  const float* Wo       = (const float*)d_in[4];
  const float* rel_bias = (const float*)d_in[5];

  char* ws = (char*)d_ws;
  bf16*  hbf    = (bf16*)(ws + 0);                 //  8 MB [4096][1024]
  bf16*  wt_qkv = (bf16*)(ws + 8388608);           //  6 MB
  bf16*  wt_o   = (bf16*)(ws + 14680064);          //  2 MB
  float* btab   = (float*)(ws + 16777216);         // 256 KB
  bf16*  qh     = (bf16*)(ws + 17039360);          //  8 MB head-major Q
  bf16*  kf     = (bf16*)(ws + 25427968);          //  8 MB frag-major K
  bf16*  vf     = (bf16*)(ws + 33816576);          //  8 MB frag-major V
  bf16*  ctx    = (bf16*)(ws + 42205184);          //  8 MB

  prep_kernel<<<dim3(8448), dim3(256), 0, stream>>>(hidden, Wq, Wk, Wv, Wo, rel_bias,
                                                    hbf, wt_qkv, wt_o, btab);
  gemm_qkv_kernel<<<dim3(24, 32), dim3(256), 0, stream>>>(hbf, wt_qkv, qh, kf, vf);
  attn_kernel<<<dim3(1024), dim3(256), 0, stream>>>(qh, kf, vf, btab, ctx);
  gemm_bt_kernel<<<dim3(8, 32), dim3(256), 0, stream>>>(ctx, wt_o, (float*)d_out, 4096, 1024, 1024);
}

// Round 9
// 196.416 us; speedup vs baseline: 1.0169x; 1.0114x over previous
//
#include <hip/hip_runtime.h>
#include <hip/hip_bf16.h>

typedef __bf16 bf16x8 __attribute__((ext_vector_type(8)));
typedef __bf16 bf16x4 __attribute__((ext_vector_type(4)));
typedef float floatx4 __attribute__((ext_vector_type(4)));
typedef float floatx16 __attribute__((ext_vector_type(16)));
using bf16 = __hip_bfloat16;

#define S_    2048
#define NHEAD 16
#define LOG2E 1.4426950408889634f

// Async global->LDS DMA, 16 B per lane (lane i -> lds + i*16).
__device__ __forceinline__ void load_lds16(const bf16* g, void* lds) {
  __builtin_amdgcn_global_load_lds((const __attribute__((address_space(1))) void*)g,
                                   (__attribute__((address_space(3))) void*)lds, 16, 0, 0);
}

// ---------------------------------------------------------------------------
// Fused prep: cast hidden fp32->bf16, transpose+cast weights, bias LUT.
// ---------------------------------------------------------------------------
__global__ void prep_kernel(const float* __restrict__ hidden,
                            const float* __restrict__ wq, const float* __restrict__ wk,
                            const float* __restrict__ wv, const float* __restrict__ wo,
                            const float* __restrict__ rel_bias,
                            bf16* __restrict__ hbf, bf16* __restrict__ wt_qkv,
                            bf16* __restrict__ wt_o, float* __restrict__ tab) {
  __shared__ bf16 tile[32][33];
  int bid = blockIdx.x;
  if (bid < 4096) {
    int i = (bid * 256 + threadIdx.x) * 4;
    float4 v = *(const float4*)(hidden + i);
    bf16 o[4] = {__float2bfloat16(v.x), __float2bfloat16(v.y),
                 __float2bfloat16(v.z), __float2bfloat16(v.w)};
    *(uint2*)(hbf + i) = *(const uint2*)o;
  } else if (bid < 8192) {
    int r = bid - 4096;
    int mat = r >> 10;
    int rem = r & 1023;
    int n0 = (rem & 31) * 32, k0 = (rem >> 5) * 32;
    int tx = threadIdx.x & 31, ty = threadIdx.x >> 5;   // 32 x 8
    const float* src = (mat == 0) ? wq : (mat == 1) ? wk : (mat == 2) ? wv : wo;
    bf16* dst = (mat == 3) ? wt_o : wt_qkv + mat * 1024 * 1024;
#pragma unroll
    for (int j = 0; j < 32; j += 8)
      tile[ty + j][tx] = __float2bfloat16(src[(k0 + ty + j) * 1024 + n0 + tx]);
    __syncthreads();
#pragma unroll
    for (int j = 0; j < 32; j += 8)
      dst[(n0 + ty + j) * 1024 + k0 + tx] = tile[tx][ty + j];
  } else {
    int idx = (bid - 8192) * 256 + threadIdx.x;  // 16*4096 = 65536
    int h = idx >> 12, j = idx & 4095;
    int delta = j - 2048;                        // k - q
    int rb = (delta > 0) ? 16 : 0;
    int rpa = delta < 0 ? -delta : delta;
    int bsmall;
    if (rpa < 8) {
      bsmall = rpa;
    } else {
      int lg = 25 - __clz(rpa * rpa);
      bsmall = 8 + lg;
      if (bsmall > 15) bsmall = 15;
    }
    tab[idx] = rel_bias[(rb + bsmall) * 16 + h] * LOG2E;
  }
}

// ---------------------------------------------------------------------------
// QKV GEMM, m97-style staging. Epilogue writes q head-major (qh[bh][s][64])
// and K/V in 32x32-MFMA fragment-major layouts:
//  kf(k,d): A-operand subtiles 32k x 16d (1KB): lane l=((d>>3)&1)*32+(k&31),
//           elem j=d&7 -> idx = (k>>5)*2048 + (d>>4)*512 + ((d>>3)&1)*256
//                              + (k&31)*8 + (d&7)
//  vf(k,d): B-operand subtiles 16k x 32d (1KB): lane l=((k>>3)&1)*32+(d&31),
//           elem j=k&7 -> idx = (k>>4)*1024 + (d>>5)*512 + ((k>>3)&1)*256
//                              + (d&31)*8 + (k&7)
// ---------------------------------------------------------------------------
__global__ __launch_bounds__(256) void gemm_qkv_kernel(const bf16* __restrict__ A,
                                                       const bf16* __restrict__ Bt,
                                                       bf16* __restrict__ qh,
                                                       bf16* __restrict__ kf,
                                                       bf16* __restrict__ vf) {
  const int K = 1024;
  __shared__ bf16 As[128 * 32];
  __shared__ bf16 Bs[128 * 32];
  int t = threadIdx.x;
  int m0 = blockIdx.y * 128, n0 = blockIdx.x * 128;
  int w = t >> 6, lane = t & 63, ln = lane & 15, quad = lane >> 4;
  int wr = w >> 1, wc = w & 1;
  floatx4 acc[4][4];
  floatx4 zero = {0.f, 0.f, 0.f, 0.f};
#pragma unroll
  for (int i = 0; i < 4; i++)
#pragma unroll
    for (int j = 0; j < 4; j++) acc[i][j] = zero;

  int r = t >> 2, c = (t & 3) * 8;
  const bf16* Ag = A + (long)(m0 + r) * K + c;
  const bf16* Bg = Bt + (long)(n0 + r) * K + c;
  char* ldsA0 = (char*)As + w * 1024;
  char* ldsA1 = ldsA0 + 4096;
  char* ldsB0 = (char*)Bs + w * 1024;
  char* ldsB1 = ldsB0 + 4096;

  for (int k0 = 0; k0 < K; k0 += 32) {
    load_lds16(Ag + k0, ldsA0);
    load_lds16(Ag + (long)64 * K + k0, ldsA1);
    load_lds16(Bg + k0, ldsB0);
    load_lds16(Bg + (long)64 * K + k0, ldsB1);
    __syncthreads();
    bf16x8 af[4], bfv[4];
#pragma unroll
    for (int i = 0; i < 4; i++)
      af[i] = *(const bf16x8*)&As[(wr * 64 + i * 16 + ln) * 32 + quad * 8];
#pragma unroll
    for (int j = 0; j < 4; j++)
      bfv[j] = *(const bf16x8*)&Bs[(wc * 64 + j * 16 + ln) * 32 + quad * 8];
#pragma unroll
    for (int i = 0; i < 4; i++)
#pragma unroll
      for (int j = 0; j < 4; j++)
        acc[i][j] = __builtin_amdgcn_mfma_f32_16x16x32_bf16(af[i], bfv[j], acc[i][j], 0, 0, 0);
    __syncthreads();
  }

  int nb = n0 + wc * 64;                        // 64-aligned column block
  int type = nb >> 10, h = (nb >> 6) & 15;
  int b = (m0 >> 11);                           // 128-tiles never straddle batch
  int sl0 = (m0 & 2047) + wr * 64;              // within-batch s base for this wave
  long bhbase = (long)((b * 16 + h)) * 131072;  // bh * 2048 * 64

  if (type == 0) {
#pragma unroll
    for (int i = 0; i < 4; i++)
#pragma unroll
      for (int j = 0; j < 4; j++) {
        int d = j * 16 + ln;
#pragma unroll
        for (int rr = 0; rr < 4; rr++) {
          int s = sl0 + i * 16 + quad * 4 + rr;
          qh[bhbase + (long)s * 64 + d] = __float2bfloat16(acc[i][j][rr]);
        }
      }
  } else if (type == 1) {
    // kf: k = sl0+i*16+quad*4+rr, d = j*16+ln
#pragma unroll
    for (int i = 0; i < 4; i++)
#pragma unroll
      for (int j = 0; j < 4; j++) {
        long base = bhbase + sl0 * 64 + (i >> 1) * 2048 + j * 512 + (ln >> 3) * 256 +
                    (i & 1) * 128 + quad * 32 + (ln & 7);
#pragma unroll
        for (int rr = 0; rr < 4; rr++)
          kf[base + rr * 8] = __float2bfloat16(acc[i][j][rr]);
      }
  } else {
    // vf: k = sl0+i*16+quad*4+rr, d = j*16+ln  (rr contiguous -> 8B store)
#pragma unroll
    for (int i = 0; i < 4; i++)
#pragma unroll
      for (int j = 0; j < 4; j++) {
        long off = sl0 * 64 + i * 1024 + (j >> 1) * 512 + (quad >> 1) * 256 +
                   ((j & 1) * 16 + ln) * 8 + (quad & 1) * 4;
        bf16x4 pk = {(__bf16)acc[i][j][0], (__bf16)acc[i][j][1],
                     (__bf16)acc[i][j][2], (__bf16)acc[i][j][3]};
        *(bf16x4*)(vf + bhbase + off) = pk;
      }
  }
}

// ---------------------------------------------------------------------------
// Flash attention v9 = r6 structure (best: 52.4us, 88 VGPR, no spill, no LDS,
// reg double-buffer KVBLK=32, XCD-ownership swizzle) + ONE new instruction:
// a raw s_barrier per 64-k iteration. Theory: every wave privately streams
// all of K+V -> 2048 waves x 64 iters x 8KB = 1.07 GB of L2 traffic (~31us at
// the 34.5 TB/s L2 ceiling) — the hidden co-limiter. The block's 4 waves read
// the SAME bh's K/V; keeping them k-aligned makes 3 of 4 reads hit L1
// (8KB/iter working set << 32KB L1) -> L2 traffic /4. Raw s_barrier does NOT
// drain vmcnt (unlike __syncthreads) so the register pipeline is preserved.
// ---------------------------------------------------------------------------
#define LOADKV(Kr, Vr, kk)                                        \
  {                                                               \
    const bf16* kp = kfb + (kk) * 64 + loff;                      \
    const bf16* vp = vfb + (kk) * 64 + loff;                      \
    Kr[0] = *(const bf16x8*)(kp);                                 \
    Kr[1] = *(const bf16x8*)(kp + 512);                           \
    Kr[2] = *(const bf16x8*)(kp + 1024);                          \
    Kr[3] = *(const bf16x8*)(kp + 1536);                          \
    Vr[0] = *(const bf16x8*)(vp);                                 \
    Vr[1] = *(const bf16x8*)(vp + 512);                           \
    Vr[2] = *(const bf16x8*)(vp + 1024);                          \
    Vr[3] = *(const bf16x8*)(vp + 1536);                          \
  }

#define COMPUTE(Kr, Vr, kk)                                                       \
  {                                                                               \
    floatx16 st = zf;                                                             \
    __builtin_amdgcn_s_setprio(1);                                                \
    st = __builtin_amdgcn_mfma_f32_32x32x16_bf16(Kr[0], Qf[0], st, 0, 0, 0);      \
    st = __builtin_amdgcn_mfma_f32_32x32x16_bf16(Kr[1], Qf[1], st, 0, 0, 0);      \
    st = __builtin_amdgcn_mfma_f32_32x32x16_bf16(Kr[2], Qf[2], st, 0, 0, 0);      \
    st = __builtin_amdgcn_mfma_f32_32x32x16_bf16(Kr[3], Qf[3], st, 0, 0, 0);      \
    __builtin_amdgcn_s_setprio(0);                                                \
    float p[16];                                                                  \
    bool near = ((kk) > qw - 160) && ((kk) < qw + 160);                           \
    if (near) {                                                                   \
      int kb = (kk) + 4 * h5 - (qw + l31) + 2048;                                 \
      _Pragma("unroll")                                                           \
      for (int r = 0; r < 16; r++)                                                \
        p[r] = __builtin_amdgcn_exp2f(                                            \
            fmaf(st[r], LOG2E, bt[kb + (r & 3) + 8 * (r >> 2)]));                 \
    } else {                                                                      \
      float cb = ((kk) > qw) ? cpos : cneg;                                       \
      _Pragma("unroll")                                                           \
      for (int r = 0; r < 16; r++)                                                \
        p[r] = __builtin_amdgcn_exp2f(fmaf(st[r], LOG2E, cb));                    \
    }                                                                             \
    float a0 = (p[0] + p[1]) + (p[2] + p[3]);                                     \
    float a1 = (p[4] + p[5]) + (p[6] + p[7]);                                     \
    float a2 = (p[8] + p[9]) + (p[10] + p[11]);                                   \
    float a3 = (p[12] + p[13]) + (p[14] + p[15]);                                 \
    l_acc += (a0 + a1) + (a2 + a3);                                               \
    unsigned d[8];                                                                \
    _Pragma("unroll")                                                             \
    for (int i = 0; i < 8; i++)                                                   \
      asm("v_cvt_pk_bf16_f32 %0, %1, %2" : "=v"(d[i]) : "v"(p[2*i]), "v"(p[2*i+1])); \
    unsigned w0 = d[0], w2 = d[2];                                                \
    asm("v_permlane32_swap_b32 %0, %1" : "+v"(w0), "+v"(w2));                     \
    unsigned w1 = d[1], w3 = d[3];                                                \
    asm("v_permlane32_swap_b32 %0, %1" : "+v"(w1), "+v"(w3));                     \
    unsigned w4 = d[4], w6 = d[6];                                                \
    asm("v_permlane32_swap_b32 %0, %1" : "+v"(w4), "+v"(w6));                     \
    unsigned w5 = d[5], w7 = d[7];                                                \
    asm("v_permlane32_swap_b32 %0, %1" : "+v"(w5), "+v"(w7));                     \
    union { unsigned u[4]; bf16x8 v; } a0u, a1u;                                  \
    a0u.u[0] = w0; a0u.u[1] = w1; a0u.u[2] = w2; a0u.u[3] = w3;                   \
    a1u.u[0] = w4; a1u.u[1] = w5; a1u.u[2] = w6; a1u.u[3] = w7;                   \
    __builtin_amdgcn_s_setprio(1);                                                \
    o0 = __builtin_amdgcn_mfma_f32_32x32x16_bf16(a0u.v, Vr[0], o0, 0, 0, 0);      \
    o1 = __builtin_amdgcn_mfma_f32_32x32x16_bf16(a0u.v, Vr[1], o1, 0, 0, 0);      \
    o0 = __builtin_amdgcn_mfma_f32_32x32x16_bf16(a1u.v, Vr[2], o0, 0, 0, 0);      \
    o1 = __builtin_amdgcn_mfma_f32_32x32x16_bf16(a1u.v, Vr[3], o1, 0, 0, 0);      \
    __builtin_amdgcn_s_setprio(0);                                                \
  }

__global__ __launch_bounds__(256, 2) void attn_kernel(const bf16* __restrict__ qh,
                                                      const bf16* __restrict__ kf,
                                                      const bf16* __restrict__ vf,
                                                      const float* __restrict__ btab,
                                                      bf16* __restrict__ ctx) {
  int t = threadIdx.x, w = t >> 6, lane = t & 63;
  int l31 = lane & 31, h5 = lane >> 5;

  // XCD-ownership swizzle: 512 blocks; xcd = lin&7 owns 4 consecutive bh.
  int lin = blockIdx.x;
  int xcd = lin & 7, j = lin >> 3;             // j in [0,64)
  int bh = xcd * 4 + (j >> 4);
  int qblk = j & 15;
  int b = bh >> 4, h = bh & 15;
  int qw = qblk * 128 + w * 32;                // this wave's first q row

  const bf16* qbase = qh + (long)bh * S_ * 64;
  const bf16* kfb = kf + (long)bh * S_ * 64;
  const bf16* vfb = vf + (long)bh * S_ * 64;
  const float* bt = btab + h * 4096;
  int loff = h5 * 256 + l31 * 8;               // lane offset inside 1KB frag (elems)

  // Q as B-operand: col = q = l31, k-of-slice = h5*8 + j (d-slice ds of 16)
  bf16x8 Qf[4];
#pragma unroll
  for (int ds = 0; ds < 4; ds++)
    Qf[ds] = *(const bf16x8*)(qbase + (long)(qw + l31) * 64 + ds * 16 + h5 * 8);

  float cneg = bt[0], cpos = bt[4095];
  float l_acc = 0.f;
  floatx16 zf = {0.f, 0.f, 0.f, 0.f, 0.f, 0.f, 0.f, 0.f,
                 0.f, 0.f, 0.f, 0.f, 0.f, 0.f, 0.f, 0.f};
  floatx16 o0 = zf, o1 = zf;

  bf16x8 Ka[4], Va[4], Kb[4], Vb[4];
  LOADKV(Ka, Va, 0);
  LOADKV(Kb, Vb, 32);

  for (int k0 = 0; k0 < S_; k0 += 64) {
    // Raw barrier (no vmcnt drain): keeps the block's 4 waves k-aligned so
    // their identical K/V fragment reads hit L1 instead of 4x L2 traffic.
    __builtin_amdgcn_s_barrier();
    COMPUTE(Ka, Va, k0);
    if (k0 + 64 < S_) LOADKV(Ka, Va, k0 + 64);
    COMPUTE(Kb, Vb, k0 + 32);
    if (k0 + 96 < S_) LOADKV(Kb, Vb, k0 + 96);
  }

  // l covers this lane's k-half only; combine halves, then broadcast per-row.
  l_acc += __shfl_xor(l_acc, 32);
  float linv = 1.0f / l_acc;                   // for q = qw + l31
#pragma unroll
  for (int r = 0; r < 16; r++) {
    int qrow = (r & 3) + 8 * (r >> 2) + 4 * h5;
    float lv = __shfl(linv, qrow);
    int q = qw + qrow;
    long base = (long)(b * S_ + q) * 1024 + h * 64 + l31;
    ctx[base] = __float2bfloat16(o0[r] * lv);
    ctx[base + 32] = __float2bfloat16(o1[r] * lv);
  }
}

// ---------------------------------------------------------------------------
// Out-proj GEMM: C[M][N] = A[M][K] * Bt[N][K]^T (fp32 out), m97-style staging.
// ---------------------------------------------------------------------------
__global__ __launch_bounds__(256) void gemm_bt_kernel(const bf16* __restrict__ A,
                                                      const bf16* __restrict__ Bt,
                                                      float* __restrict__ C,
                                                      int M, int N, int K) {
  __shared__ bf16 As[128 * 32];
  __shared__ bf16 Bs[128 * 32];
  int t = threadIdx.x;
  int m0 = blockIdx.y * 128, n0 = blockIdx.x * 128;
  int w = t >> 6, lane = t & 63, ln = lane & 15, quad = lane >> 4;
  int wr = w >> 1, wc = w & 1;
  floatx4 acc[4][4];
  floatx4 zero = {0.f, 0.f, 0.f, 0.f};
#pragma unroll
  for (int i = 0; i < 4; i++)
#pragma unroll
    for (int j = 0; j < 4; j++) acc[i][j] = zero;

  int r = t >> 2, c = (t & 3) * 8;
  const bf16* Ag = A + (long)(m0 + r) * K + c;
  const bf16* Bg = Bt + (long)(n0 + r) * K + c;
  char* ldsA0 = (char*)As + w * 1024;
  char* ldsA1 = ldsA0 + 4096;
  char* ldsB0 = (char*)Bs + w * 1024;
  char* ldsB1 = ldsB0 + 4096;

  for (int k0 = 0; k0 < K; k0 += 32) {
    load_lds16(Ag + k0, ldsA0);
    load_lds16(Ag + (long)64 * K + k0, ldsA1);
    load_lds16(Bg + k0, ldsB0);
    load_lds16(Bg + (long)64 * K + k0, ldsB1);
    __syncthreads();
    bf16x8 af[4], bfv[4];
#pragma unroll
    for (int i = 0; i < 4; i++)
      af[i] = *(const bf16x8*)&As[(wr * 64 + i * 16 + ln) * 32 + quad * 8];
#pragma unroll
    for (int j = 0; j < 4; j++)
      bfv[j] = *(const bf16x8*)&Bs[(wc * 64 + j * 16 + ln) * 32 + quad * 8];
#pragma unroll
    for (int i = 0; i < 4; i++)
#pragma unroll
      for (int j = 0; j < 4; j++)
        acc[i][j] = __builtin_amdgcn_mfma_f32_16x16x32_bf16(af[i], bfv[j], acc[i][j], 0, 0, 0);
    __syncthreads();
  }

#pragma unroll
  for (int i = 0; i < 4; i++)
#pragma unroll
    for (int j = 0; j < 4; j++)
#pragma unroll
      for (int rr = 0; rr < 4; rr++)
        C[(long)(m0 + wr * 64 + i * 16 + quad * 4 + rr) * N + n0 + wc * 64 + j * 16 + ln] =
            acc[i][j][rr];
}

// ---------------------------------------------------------------------------
extern "C" void kernel_launch(void* const* d_in, const int* in_sizes, int n_in,
                              void* d_out, int out_size, void* d_ws, size_t ws_size,
                              hipStream_t stream) {
  (void)in_sizes; (void)n_in; (void)out_size; (void)ws_size;
  const float* hidden   = (const float*)d_in[0];
  const float* Wq       = (const float*)d_in[1];
  const float* Wk       = (const float*)d_in[2];
  const float* Wv       = (const float*)d_in[3];
  const float* Wo       = (const float*)d_in[4];
  const float* rel_bias = (const float*)d_in[5];

  char* ws = (char*)d_ws;
  bf16*  hbf    = (bf16*)(ws + 0);                 //  8 MB [4096][1024]
  bf16*  wt_qkv = (bf16*)(ws + 8388608);           //  6 MB
  bf16*  wt_o   = (bf16*)(ws + 14680064);          //  2 MB
  float* btab   = (float*)(ws + 16777216);         // 256 KB
  bf16*  qh     = (bf16*)(ws + 17039360);          //  8 MB head-major Q
  bf16*  kf     = (bf16*)(ws + 25427968);          //  8 MB frag-major K
  bf16*  vf     = (bf16*)(ws + 33816576);          //  8 MB frag-major V
  bf16*  ctx    = (bf16*)(ws + 42205184);          //  8 MB

  prep_kernel<<<dim3(8448), dim3(256), 0, stream>>>(hidden, Wq, Wk, Wv, Wo, rel_bias,
                                                    hbf, wt_qkv, wt_o, btab);
  gemm_qkv_kernel<<<dim3(24, 32), dim3(256), 0, stream>>>(hbf, wt_qkv, qh, kf, vf);
  attn_kernel<<<dim3(512), dim3(256), 0, stream>>>(qh, kf, vf, btab, ctx);
  gemm_bt_kernel<<<dim3(8, 32), dim3(256), 0, stream>>>(ctx, wt_o, (float*)d_out, 4096, 1024, 1024);
}

// Round 10
// 188.364 us; speedup vs baseline: 1.0604x; 1.0428x over previous
//
#include <hip/hip_runtime.h>
#include <hip/hip_bf16.h>

typedef __bf16 bf16x8 __attribute__((ext_vector_type(8)));
typedef __bf16 bf16x4 __attribute__((ext_vector_type(4)));
typedef float floatx4 __attribute__((ext_vector_type(4)));
typedef float floatx16 __attribute__((ext_vector_type(16)));
using bf16 = __hip_bfloat16;

#define S_    2048
#define NHEAD 16
#define LOG2E 1.4426950408889634f

// Async global->LDS DMA, 16 B per lane (lane i -> lds + i*16).
__device__ __forceinline__ void load_lds16(const bf16* g, void* lds) {
  __builtin_amdgcn_global_load_lds((const __attribute__((address_space(1))) void*)g,
                                   (__attribute__((address_space(3))) void*)lds, 16, 0, 0);
}

// ---------------------------------------------------------------------------
// Fused prep: cast hidden fp32->bf16, transpose+cast weights, bias LUT.
// ---------------------------------------------------------------------------
__global__ void prep_kernel(const float* __restrict__ hidden,
                            const float* __restrict__ wq, const float* __restrict__ wk,
                            const float* __restrict__ wv, const float* __restrict__ wo,
                            const float* __restrict__ rel_bias,
                            bf16* __restrict__ hbf, bf16* __restrict__ wt_qkv,
                            bf16* __restrict__ wt_o, float* __restrict__ tab) {
  __shared__ bf16 tile[32][33];
  int bid = blockIdx.x;
  if (bid < 4096) {
    int i = (bid * 256 + threadIdx.x) * 4;
    float4 v = *(const float4*)(hidden + i);
    bf16 o[4] = {__float2bfloat16(v.x), __float2bfloat16(v.y),
                 __float2bfloat16(v.z), __float2bfloat16(v.w)};
    *(uint2*)(hbf + i) = *(const uint2*)o;
  } else if (bid < 8192) {
    int r = bid - 4096;
    int mat = r >> 10;
    int rem = r & 1023;
    int n0 = (rem & 31) * 32, k0 = (rem >> 5) * 32;
    int tx = threadIdx.x & 31, ty = threadIdx.x >> 5;   // 32 x 8
    const float* src = (mat == 0) ? wq : (mat == 1) ? wk : (mat == 2) ? wv : wo;
    bf16* dst = (mat == 3) ? wt_o : wt_qkv + mat * 1024 * 1024;
#pragma unroll
    for (int j = 0; j < 32; j += 8)
      tile[ty + j][tx] = __float2bfloat16(src[(k0 + ty + j) * 1024 + n0 + tx]);
    __syncthreads();
#pragma unroll
    for (int j = 0; j < 32; j += 8)
      dst[(n0 + ty + j) * 1024 + k0 + tx] = tile[tx][ty + j];
  } else {
    int idx = (bid - 8192) * 256 + threadIdx.x;  // 16*4096 = 65536
    int h = idx >> 12, j = idx & 4095;
    int delta = j - 2048;                        // k - q
    int rb = (delta > 0) ? 16 : 0;
    int rpa = delta < 0 ? -delta : delta;
    int bsmall;
    if (rpa < 8) {
      bsmall = rpa;
    } else {
      int lg = 25 - __clz(rpa * rpa);
      bsmall = 8 + lg;
      if (bsmall > 15) bsmall = 15;
    }
    tab[idx] = rel_bias[(rb + bsmall) * 16 + h] * LOG2E;
  }
}

// ---------------------------------------------------------------------------
// QKV GEMM, m97-style staging. Epilogue writes q head-major (qh[bh][s][64])
// and K/V in 32x32-MFMA fragment-major layouts:
//  kf(k,d): A-operand subtiles 32k x 16d (1KB): lane l=((d>>3)&1)*32+(k&31),
//           elem j=d&7 -> idx = (k>>5)*2048 + (d>>4)*512 + ((d>>3)&1)*256
//                              + (k&31)*8 + (d&7)
//  vf(k,d): B-operand subtiles 16k x 32d (1KB): lane l=((k>>3)&1)*32+(d&31),
//           elem j=k&7 -> idx = (k>>4)*1024 + (d>>5)*512 + ((k>>3)&1)*256
//                              + (d&31)*8 + (k&7)
// ---------------------------------------------------------------------------
__global__ __launch_bounds__(256) void gemm_qkv_kernel(const bf16* __restrict__ A,
                                                       const bf16* __restrict__ Bt,
                                                       bf16* __restrict__ qh,
                                                       bf16* __restrict__ kf,
                                                       bf16* __restrict__ vf) {
  const int K = 1024;
  __shared__ bf16 As[128 * 32];
  __shared__ bf16 Bs[128 * 32];
  int t = threadIdx.x;
  int m0 = blockIdx.y * 128, n0 = blockIdx.x * 128;
  int w = t >> 6, lane = t & 63, ln = lane & 15, quad = lane >> 4;
  int wr = w >> 1, wc = w & 1;
  floatx4 acc[4][4];
  floatx4 zero = {0.f, 0.f, 0.f, 0.f};
#pragma unroll
  for (int i = 0; i < 4; i++)
#pragma unroll
    for (int j = 0; j < 4; j++) acc[i][j] = zero;

  int r = t >> 2, c = (t & 3) * 8;
  const bf16* Ag = A + (long)(m0 + r) * K + c;
  const bf16* Bg = Bt + (long)(n0 + r) * K + c;
  char* ldsA0 = (char*)As + w * 1024;
  char* ldsA1 = ldsA0 + 4096;
  char* ldsB0 = (char*)Bs + w * 1024;
  char* ldsB1 = ldsB0 + 4096;

  for (int k0 = 0; k0 < K; k0 += 32) {
    load_lds16(Ag + k0, ldsA0);
    load_lds16(Ag + (long)64 * K + k0, ldsA1);
    load_lds16(Bg + k0, ldsB0);
    load_lds16(Bg + (long)64 * K + k0, ldsB1);
    __syncthreads();
    bf16x8 af[4], bfv[4];
#pragma unroll
    for (int i = 0; i < 4; i++)
      af[i] = *(const bf16x8*)&As[(wr * 64 + i * 16 + ln) * 32 + quad * 8];
#pragma unroll
    for (int j = 0; j < 4; j++)
      bfv[j] = *(const bf16x8*)&Bs[(wc * 64 + j * 16 + ln) * 32 + quad * 8];
#pragma unroll
    for (int i = 0; i < 4; i++)
#pragma unroll
      for (int j = 0; j < 4; j++)
        acc[i][j] = __builtin_amdgcn_mfma_f32_16x16x32_bf16(af[i], bfv[j], acc[i][j], 0, 0, 0);
    __syncthreads();
  }

  int nb = n0 + wc * 64;                        // 64-aligned column block
  int type = nb >> 10, h = (nb >> 6) & 15;
  int b = (m0 >> 11);                           // 128-tiles never straddle batch
  int sl0 = (m0 & 2047) + wr * 64;              // within-batch s base for this wave
  long bhbase = (long)((b * 16 + h)) * 131072;  // bh * 2048 * 64

  if (type == 0) {
#pragma unroll
    for (int i = 0; i < 4; i++)
#pragma unroll
      for (int j = 0; j < 4; j++) {
        int d = j * 16 + ln;
#pragma unroll
        for (int rr = 0; rr < 4; rr++) {
          int s = sl0 + i * 16 + quad * 4 + rr;
          qh[bhbase + (long)s * 64 + d] = __float2bfloat16(acc[i][j][rr]);
        }
      }
  } else if (type == 1) {
    // kf: k = sl0+i*16+quad*4+rr, d = j*16+ln
#pragma unroll
    for (int i = 0; i < 4; i++)
#pragma unroll
      for (int j = 0; j < 4; j++) {
        long base = bhbase + sl0 * 64 + (i >> 1) * 2048 + j * 512 + (ln >> 3) * 256 +
                    (i & 1) * 128 + quad * 32 + (ln & 7);
#pragma unroll
        for (int rr = 0; rr < 4; rr++)
          kf[base + rr * 8] = __float2bfloat16(acc[i][j][rr]);
      }
  } else {
    // vf: k = sl0+i*16+quad*4+rr, d = j*16+ln  (rr contiguous -> 8B store)
#pragma unroll
    for (int i = 0; i < 4; i++)
#pragma unroll
      for (int j = 0; j < 4; j++) {
        long off = sl0 * 64 + i * 1024 + (j >> 1) * 512 + (quad >> 1) * 256 +
                   ((j & 1) * 16 + ln) * 8 + (quad & 1) * 4;
        bf16x4 pk = {(__bf16)acc[i][j][0], (__bf16)acc[i][j][1],
                     (__bf16)acc[i][j][2], (__bf16)acc[i][j][3]};
        *(bf16x4*)(vf + bhbase + off) = pk;
      }
  }
}

// ---------------------------------------------------------------------------
// Flash attention v10 = exact r6 revert (best measured: 52.4us, 88 VGPR, no
// spill, no LDS, no barriers, reg double-buffer KVBLK=32, XCD-ownership
// swizzle). r7 (k-split), r8 (single-buffer+k-split), r9 (s_barrier L1-align)
// all measured worse -> this decomposition's plateau; leave it.
// ---------------------------------------------------------------------------
#define LOADKV(Kr, Vr, kk)                                        \
  {                                                               \
    const bf16* kp = kfb + (kk) * 64 + loff;                      \
    const bf16* vp = vfb + (kk) * 64 + loff;                      \
    Kr[0] = *(const bf16x8*)(kp);                                 \
    Kr[1] = *(const bf16x8*)(kp + 512);                           \
    Kr[2] = *(const bf16x8*)(kp + 1024);                          \
    Kr[3] = *(const bf16x8*)(kp + 1536);                          \
    Vr[0] = *(const bf16x8*)(vp);                                 \
    Vr[1] = *(const bf16x8*)(vp + 512);                           \
    Vr[2] = *(const bf16x8*)(vp + 1024);                          \
    Vr[3] = *(const bf16x8*)(vp + 1536);                          \
  }

#define COMPUTE(Kr, Vr, kk)                                                       \
  {                                                                               \
    floatx16 st = zf;                                                             \
    __builtin_amdgcn_s_setprio(1);                                                \
    st = __builtin_amdgcn_mfma_f32_32x32x16_bf16(Kr[0], Qf[0], st, 0, 0, 0);      \
    st = __builtin_amdgcn_mfma_f32_32x32x16_bf16(Kr[1], Qf[1], st, 0, 0, 0);      \
    st = __builtin_amdgcn_mfma_f32_32x32x16_bf16(Kr[2], Qf[2], st, 0, 0, 0);      \
    st = __builtin_amdgcn_mfma_f32_32x32x16_bf16(Kr[3], Qf[3], st, 0, 0, 0);      \
    __builtin_amdgcn_s_setprio(0);                                                \
    float p[16];                                                                  \
    bool near = ((kk) > qw - 160) && ((kk) < qw + 160);                           \
    if (near) {                                                                   \
      int kb = (kk) + 4 * h5 - (qw + l31) + 2048;                                 \
      _Pragma("unroll")                                                           \
      for (int r = 0; r < 16; r++)                                                \
        p[r] = __builtin_amdgcn_exp2f(                                            \
            fmaf(st[r], LOG2E, bt[kb + (r & 3) + 8 * (r >> 2)]));                 \
    } else {                                                                      \
      float cb = ((kk) > qw) ? cpos : cneg;                                       \
      _Pragma("unroll")                                                           \
      for (int r = 0; r < 16; r++)                                                \
        p[r] = __builtin_amdgcn_exp2f(fmaf(st[r], LOG2E, cb));                    \
    }                                                                             \
    float a0 = (p[0] + p[1]) + (p[2] + p[3]);                                     \
    float a1 = (p[4] + p[5]) + (p[6] + p[7]);                                     \
    float a2 = (p[8] + p[9]) + (p[10] + p[11]);                                   \
    float a3 = (p[12] + p[13]) + (p[14] + p[15]);                                 \
    l_acc += (a0 + a1) + (a2 + a3);                                               \
    unsigned d[8];                                                                \
    _Pragma("unroll")                                                             \
    for (int i = 0; i < 8; i++)                                                   \
      asm("v_cvt_pk_bf16_f32 %0, %1, %2" : "=v"(d[i]) : "v"(p[2*i]), "v"(p[2*i+1])); \
    unsigned w0 = d[0], w2 = d[2];                                                \
    asm("v_permlane32_swap_b32 %0, %1" : "+v"(w0), "+v"(w2));                     \
    unsigned w1 = d[1], w3 = d[3];                                                \
    asm("v_permlane32_swap_b32 %0, %1" : "+v"(w1), "+v"(w3));                     \
    unsigned w4 = d[4], w6 = d[6];                                                \
    asm("v_permlane32_swap_b32 %0, %1" : "+v"(w4), "+v"(w6));                     \
    unsigned w5 = d[5], w7 = d[7];                                                \
    asm("v_permlane32_swap_b32 %0, %1" : "+v"(w5), "+v"(w7));                     \
    union { unsigned u[4]; bf16x8 v; } a0u, a1u;                                  \
    a0u.u[0] = w0; a0u.u[1] = w1; a0u.u[2] = w2; a0u.u[3] = w3;                   \
    a1u.u[0] = w4; a1u.u[1] = w5; a1u.u[2] = w6; a1u.u[3] = w7;                   \
    __builtin_amdgcn_s_setprio(1);                                                \
    o0 = __builtin_amdgcn_mfma_f32_32x32x16_bf16(a0u.v, Vr[0], o0, 0, 0, 0);      \
    o1 = __builtin_amdgcn_mfma_f32_32x32x16_bf16(a0u.v, Vr[1], o1, 0, 0, 0);      \
    o0 = __builtin_amdgcn_mfma_f32_32x32x16_bf16(a1u.v, Vr[2], o0, 0, 0, 0);      \
    o1 = __builtin_amdgcn_mfma_f32_32x32x16_bf16(a1u.v, Vr[3], o1, 0, 0, 0);      \
    __builtin_amdgcn_s_setprio(0);                                                \
  }

__global__ __launch_bounds__(256, 2) void attn_kernel(const bf16* __restrict__ qh,
                                                      const bf16* __restrict__ kf,
                                                      const bf16* __restrict__ vf,
                                                      const float* __restrict__ btab,
                                                      bf16* __restrict__ ctx) {
  int t = threadIdx.x, w = t >> 6, lane = t & 63;
  int l31 = lane & 31, h5 = lane >> 5;

  // XCD-ownership swizzle: 512 blocks; xcd = lin&7 owns 4 consecutive bh.
  int lin = blockIdx.x;
  int xcd = lin & 7, j = lin >> 3;             // j in [0,64)
  int bh = xcd * 4 + (j >> 4);
  int qblk = j & 15;
  int b = bh >> 4, h = bh & 15;
  int qw = qblk * 128 + w * 32;                // this wave's first q row

  const bf16* qbase = qh + (long)bh * S_ * 64;
  const bf16* kfb = kf + (long)bh * S_ * 64;
  const bf16* vfb = vf + (long)bh * S_ * 64;
  const float* bt = btab + h * 4096;
  int loff = h5 * 256 + l31 * 8;               // lane offset inside 1KB frag (elems)

  // Q as B-operand: col = q = l31, k-of-slice = h5*8 + j (d-slice ds of 16)
  bf16x8 Qf[4];
#pragma unroll
  for (int ds = 0; ds < 4; ds++)
    Qf[ds] = *(const bf16x8*)(qbase + (long)(qw + l31) * 64 + ds * 16 + h5 * 8);

  float cneg = bt[0], cpos = bt[4095];
  float l_acc = 0.f;
  floatx16 zf = {0.f, 0.f, 0.f, 0.f, 0.f, 0.f, 0.f, 0.f,
                 0.f, 0.f, 0.f, 0.f, 0.f, 0.f, 0.f, 0.f};
  floatx16 o0 = zf, o1 = zf;

  bf16x8 Ka[4], Va[4], Kb[4], Vb[4];
  LOADKV(Ka, Va, 0);
  LOADKV(Kb, Vb, 32);

  for (int k0 = 0; k0 < S_; k0 += 64) {
    COMPUTE(Ka, Va, k0);
    if (k0 + 64 < S_) LOADKV(Ka, Va, k0 + 64);
    COMPUTE(Kb, Vb, k0 + 32);
    if (k0 + 96 < S_) LOADKV(Kb, Vb, k0 + 96);
  }

  // l covers this lane's k-half only; combine halves, then broadcast per-row.
  l_acc += __shfl_xor(l_acc, 32);
  float linv = 1.0f / l_acc;                   // for q = qw + l31
#pragma unroll
  for (int r = 0; r < 16; r++) {
    int qrow = (r & 3) + 8 * (r >> 2) + 4 * h5;
    float lv = __shfl(linv, qrow);
    int q = qw + qrow;
    long base = (long)(b * S_ + q) * 1024 + h * 64 + l31;
    ctx[base] = __float2bfloat16(o0[r] * lv);
    ctx[base + 32] = __float2bfloat16(o1[r] * lv);
  }
}

// ---------------------------------------------------------------------------
// Out-proj GEMM v2: C[M][N] = A[M][K] * Bt[N][K]^T (fp32 out).
// r9 analysis: old grid (8,32)=256 blocks = 1 block/CU = 1 wave/SIMD -> pure
// latency exposure, ~30us for 8.6 GFLOP. Re-tiled BM=64 x BN=128 -> grid
// (8,64)=512 blocks = 2 blocks/CU = 2 waves/SIMD. Per wave: 32x64 output
// (acc[2][4], 8 MFMA/k-step). LDS 12KB; A-staging 1 load/thread, B 2.
// ---------------------------------------------------------------------------
__global__ __launch_bounds__(256) void gemm_bt_kernel(const bf16* __restrict__ A,
                                                      const bf16* __restrict__ Bt,
                                                      float* __restrict__ C,
                                                      int M, int N, int K) {
  __shared__ bf16 As[64 * 32];
  __shared__ bf16 Bs[128 * 32];
  int t = threadIdx.x;
  int m0 = blockIdx.y * 64, n0 = blockIdx.x * 128;
  int w = t >> 6, lane = t & 63, ln = lane & 15, quad = lane >> 4;
  int wr = w & 1, wc = w >> 1;                 // wave = 32 rows x 64 cols
  floatx4 acc[2][4];
  floatx4 zero = {0.f, 0.f, 0.f, 0.f};
#pragma unroll
  for (int i = 0; i < 2; i++)
#pragma unroll
    for (int j = 0; j < 4; j++) acc[i][j] = zero;

  int r = t >> 2, c = (t & 3) * 8;             // r in [0,64), c in {0,8,16,24}
  const bf16* Ag = A + (long)(m0 + r) * K + c;
  const bf16* Bg = Bt + (long)(n0 + r) * K + c;
  char* ldsA0 = (char*)As + w * 1024;
  char* ldsB0 = (char*)Bs + w * 1024;
  char* ldsB1 = ldsB0 + 4096;

  for (int k0 = 0; k0 < K; k0 += 32) {
    load_lds16(Ag + k0, ldsA0);
    load_lds16(Bg + k0, ldsB0);
    load_lds16(Bg + (long)64 * K + k0, ldsB1);
    __syncthreads();
    bf16x8 af[2], bfv[4];
#pragma unroll
    for (int i = 0; i < 2; i++)
      af[i] = *(const bf16x8*)&As[(wr * 32 + i * 16 + ln) * 32 + quad * 8];
#pragma unroll
    for (int j = 0; j < 4; j++)
      bfv[j] = *(const bf16x8*)&Bs[(wc * 64 + j * 16 + ln) * 32 + quad * 8];
#pragma unroll
    for (int i = 0; i < 2; i++)
#pragma unroll
      for (int j = 0; j < 4; j++)
        acc[i][j] = __builtin_amdgcn_mfma_f32_16x16x32_bf16(af[i], bfv[j], acc[i][j], 0, 0, 0);
    __syncthreads();
  }

#pragma unroll
  for (int i = 0; i < 2; i++)
#pragma unroll
    for (int j = 0; j < 4; j++)
#pragma unroll
      for (int rr = 0; rr < 4; rr++)
        C[(long)(m0 + wr * 32 + i * 16 + quad * 4 + rr) * N + n0 + wc * 64 + j * 16 + ln] =
            acc[i][j][rr];
}

// ---------------------------------------------------------------------------
extern "C" void kernel_launch(void* const* d_in, const int* in_sizes, int n_in,
                              void* d_out, int out_size, void* d_ws, size_t ws_size,
                              hipStream_t stream) {
  (void)in_sizes; (void)n_in; (void)out_size; (void)ws_size;
  const float* hidden   = (const float*)d_in[0];
  const float* Wq       = (const float*)d_in[1];
  const float* Wk       = (const float*)d_in[2];
  const float* Wv       = (const float*)d_in[3];
  const float* Wo       = (const float*)d_in[4];
  const float* rel_bias = (const float*)d_in[5];

  char* ws = (char*)d_ws;
  bf16*  hbf    = (bf16*)(ws + 0);                 //  8 MB [4096][1024]
  bf16*  wt_qkv = (bf16*)(ws + 8388608);           //  6 MB
  bf16*  wt_o   = (bf16*)(ws + 14680064);          //  2 MB
  float* btab   = (float*)(ws + 16777216);         // 256 KB
  bf16*  qh     = (bf16*)(ws + 17039360);          //  8 MB head-major Q
  bf16*  kf     = (bf16*)(ws + 25427968);          //  8 MB frag-major K
  bf16*  vf     = (bf16*)(ws + 33816576);          //  8 MB frag-major V
  bf16*  ctx    = (bf16*)(ws + 42205184);          //  8 MB

  prep_kernel<<<dim3(8448), dim3(256), 0, stream>>>(hidden, Wq, Wk, Wv, Wo, rel_bias,
                                                    hbf, wt_qkv, wt_o, btab);
  gemm_qkv_kernel<<<dim3(24, 32), dim3(256), 0, stream>>>(hbf, wt_qkv, qh, kf, vf);
  attn_kernel<<<dim3(512), dim3(256), 0, stream>>>(qh, kf, vf, btab, ctx);
  gemm_bt_kernel<<<dim3(8, 64), dim3(256), 0, stream>>>(ctx, wt_o, (float*)d_out, 4096, 1024, 1024);
}